// Round 7
// baseline (159.579 us; speedup 1.0000x reference)
//
#include <hip/hip_runtime.h>
#include <math.h>

// Problem constants (reference: N=64, H=512, W=512, RATIO=2, ITERATIONS=1)
#define NIMG 64
#define HH 512
#define WW 512
#define NPIX (NIMG * HH * WW)          // 16,777,216
#define NTHREADS (NPIX / 4)            // 4 px per thread
#define NBLK (NTHREADS / 256)          // 16,384 blocks
#define INV_TOTAL (1.0f / 16777216.0f) // exact pow2

// Fully elementwise formulation, no LDS tile, no barrier, no phases.
// y ∈ {0,1}:  has_one(3x3 valid) = OR of raw y;  has_zero = (AND == 0).
// cv2 clipped border == replicate padding for idempotent OR/AND, so all
// edge handling is pure address clamping — zero mask instructions.
// border = has_one & has_zero;  w = 1 + border.
__global__ __launch_bounds__(256, 8) void border_loss_main(
    const float* __restrict__ x, const int* __restrict__ y,
    float* __restrict__ part, int atomic_mode)
{
    __shared__ float wsum[4];

    const int tid = threadIdx.x;
    const int idx = blockIdx.x * 256 + tid;
    const int g   = idx & 127;               // int4 group within row
    const int r   = (idx >> 7) & (HH - 1);   // row
    const int n   = idx >> 16;               // image
    const int rowb = n * (HH * WW) + r * WW; // < 2^24, int-safe
    const int c0  = g << 2;

    // clamped (replicate) offsets — idempotent OR/AND make this exact
    const int offT = (r > 0)      ? -WW : 0;
    const int offB = (r < HH - 1) ?  WW : 0;
    const int cL   = (g == 0)     ? 0        : (c0 - 1);
    const int cR   = (g == 127)   ? (WW - 1) : (c0 + 4);

    // ---- 10 independent loads, all feeding one straight-line computation
    const int4 yC = *(const int4*)(y + rowb + c0);
    const int4 yT = *(const int4*)(y + rowb + offT + c0);
    const int4 yB = *(const int4*)(y + rowb + offB + c0);
    const int yCL = y[rowb + cL];
    const int yTL = y[rowb + offT + cL];
    const int yBL = y[rowb + offB + cL];
    const int yCR = y[rowb + cR];
    const int yTR = y[rowb + offT + cR];
    const int yBR = y[rowb + offB + cR];
    const float4 xv = *(const float4*)(x + rowb + c0);

    // ---- vertical OR / AND (per column)
    const int vo0 = yT.x | yC.x | yB.x;
    const int vo1 = yT.y | yC.y | yB.y;
    const int vo2 = yT.z | yC.z | yB.z;
    const int vo3 = yT.w | yC.w | yB.w;
    const int va0 = yT.x & yC.x & yB.x;
    const int va1 = yT.y & yC.y & yB.y;
    const int va2 = yT.z & yC.z & yB.z;
    const int va3 = yT.w & yC.w & yB.w;
    const int voL = yTL | yCL | yBL;
    const int vaL = yTL & yCL & yBL;
    const int voR = yTR | yCR | yBR;
    const int vaR = yTR & yCR & yBR;

    // ---- horizontal 3-window OR / AND
    const int ho0 = voL | vo0 | vo1;
    const int ho1 = vo0 | vo1 | vo2;
    const int ho2 = vo1 | vo2 | vo3;
    const int ho3 = vo2 | vo3 | voR;
    const int ha0 = vaL & va0 & va1;
    const int ha1 = va0 & va1 & va2;
    const int ha2 = va1 & va2 & va3;
    const int ha3 = va2 & va3 & vaR;

    // ---- per-pixel loss: max(x,0) - x*y + ln(1+e^{-|x|}); weight 2 on border
    float acc;
    {
        const float xf = xv.x;
        const float lg = __logf(1.0f + __expf(-fabsf(xf)));
        const float ls = fmaxf(xf, 0.0f) - (yC.x ? xf : 0.0f) + lg;
        const bool bd = (ho0 != 0) & (ha0 == 0);
        acc = ls * (bd ? 2.0f : 1.0f);
    }
    {
        const float xf = xv.y;
        const float lg = __logf(1.0f + __expf(-fabsf(xf)));
        const float ls = fmaxf(xf, 0.0f) - (yC.y ? xf : 0.0f) + lg;
        const bool bd = (ho1 != 0) & (ha1 == 0);
        acc = fmaf(ls, bd ? 2.0f : 1.0f, acc);
    }
    {
        const float xf = xv.z;
        const float lg = __logf(1.0f + __expf(-fabsf(xf)));
        const float ls = fmaxf(xf, 0.0f) - (yC.z ? xf : 0.0f) + lg;
        const bool bd = (ho2 != 0) & (ha2 == 0);
        acc = fmaf(ls, bd ? 2.0f : 1.0f, acc);
    }
    {
        const float xf = xv.w;
        const float lg = __logf(1.0f + __expf(-fabsf(xf)));
        const float ls = fmaxf(xf, 0.0f) - (yC.w ? xf : 0.0f) + lg;
        const bool bd = (ho3 != 0) & (ha3 == 0);
        acc = fmaf(ls, bd ? 2.0f : 1.0f, acc);
    }

    // ---- reduction: wave shuffle + tiny LDS across 4 waves
    #pragma unroll
    for (int off = 32; off > 0; off >>= 1)
        acc += __shfl_down(acc, off);
    if ((tid & 63) == 0) wsum[tid >> 6] = acc;
    __syncthreads();
    if (tid == 0) {
        const float t = wsum[0] + wsum[1] + wsum[2] + wsum[3];
        if (atomic_mode) atomicAdd(part, t * INV_TOTAL);
        else             part[blockIdx.x] = t;
    }
}

__global__ __launch_bounds__(256) void border_loss_reduce(
    const float* __restrict__ part, float* __restrict__ out)
{
    __shared__ float wsum[4];
    float t = 0.0f;
    for (int i = threadIdx.x; i < NBLK; i += 256) t += part[i];
    #pragma unroll
    for (int off = 32; off > 0; off >>= 1)
        t += __shfl_down(t, off);
    if ((threadIdx.x & 63) == 0) wsum[threadIdx.x >> 6] = t;
    __syncthreads();
    if (threadIdx.x == 0)
        out[0] = (wsum[0] + wsum[1] + wsum[2] + wsum[3]) * INV_TOTAL;
}

__global__ void border_loss_zero(float* out) { out[0] = 0.0f; }

extern "C" void kernel_launch(void* const* d_in, const int* in_sizes, int n_in,
                              void* d_out, int out_size, void* d_ws, size_t ws_size,
                              hipStream_t stream)
{
    const float* x = (const float*)d_in[0];
    const int*   y = (const int*)d_in[1];
    float* out = (float*)d_out;

    if (ws_size >= (size_t)NBLK * sizeof(float)) {
        // Deterministic two-stage reduction via workspace partials.
        float* part = (float*)d_ws;
        border_loss_main<<<NBLK, 256, 0, stream>>>(x, y, part, 0);
        border_loss_reduce<<<1, 256, 0, stream>>>(part, out);
    } else {
        // Fallback: zero output then atomic accumulation.
        border_loss_zero<<<1, 1, 0, stream>>>(out);
        border_loss_main<<<NBLK, 256, 0, stream>>>(x, y, out, 1);
    }
}

// Round 8
// 148.487 us; speedup vs baseline: 1.0747x; 1.0747x over previous
//
#include <hip/hip_runtime.h>
#include <math.h>

// Problem constants (reference: N=64, H=512, W=512, RATIO=2, ITERATIONS=1)
#define NIMG 64
#define HH 512
#define WW 512
#define NBLK 8192                      // 2^21 threads, 8 px each
#define INV_TOTAL (1.0f / 16777216.0f) // exact pow2

// Fully elementwise, one wave == one image row (64 lanes x 8 px = 512 cols).
// y ∈ {0,1}: has_one(valid 3x3) = OR, all_one = AND; border = OR ^ AND.
// cv2 clipped border == replicate padding for idempotent OR/AND:
//   rows: address clamp; cols: lane shfl with self-replication at lanes 0/63.
// No LDS tile, no barrier, no scalar gathers.
__global__ __launch_bounds__(256, 8) void border_loss_main(
    const float* __restrict__ x, const int* __restrict__ y,
    float* __restrict__ part, int atomic_mode)
{
    __shared__ float wsum[4];

    const int tid  = threadIdx.x;
    const int idx  = blockIdx.x * 256 + tid;
    const int lane = tid & 63;               // == idx & 63 (256-aligned blocks)
    const int r    = (idx >> 6) & (HH - 1);  // image row (one per wave)
    const int n    = idx >> 15;              // image
    const int rowb = n * (HH * WW) + r * WW; // < 2^24, int-safe
    const int col  = lane << 3;              // first of 8 owned columns

    const int pC = rowb + col;
    const int pT = pC + ((r > 0)      ? -WW : 0);   // replicate row clamp
    const int pB = pC + ((r < HH - 1) ?  WW : 0);

    // ---- 8 dense coalesced loads (all independent)
    const int4   t0 = *(const int4*)(y + pT);
    const int4   t1 = *(const int4*)(y + pT + 4);
    const int4   c0 = *(const int4*)(y + pC);
    const int4   c1 = *(const int4*)(y + pC + 4);
    const int4   b0 = *(const int4*)(y + pB);
    const int4   b1 = *(const int4*)(y + pB + 4);
    const float4 xa = *(const float4*)(x + pC);
    const float4 xb = *(const float4*)(x + pC + 4);

    // ---- vertical OR / AND per owned column
    const int vo0 = t0.x | c0.x | b0.x;  const int va0 = t0.x & c0.x & b0.x;
    const int vo1 = t0.y | c0.y | b0.y;  const int va1 = t0.y & c0.y & b0.y;
    const int vo2 = t0.z | c0.z | b0.z;  const int va2 = t0.z & c0.z & b0.z;
    const int vo3 = t0.w | c0.w | b0.w;  const int va3 = t0.w & c0.w & b0.w;
    const int vo4 = t1.x | c1.x | b1.x;  const int va4 = t1.x & c1.x & b1.x;
    const int vo5 = t1.y | c1.y | b1.y;  const int va5 = t1.y & c1.y & b1.y;
    const int vo6 = t1.z | c1.z | b1.z;  const int va6 = t1.z & c1.z & b1.z;
    const int vo7 = t1.w | c1.w | b1.w;  const int va7 = t1.w & c1.w & b1.w;

    // ---- neighbor columns across lanes (wave edge == image edge: replicate)
    const int iL = (lane + 63) & 63, iR = (lane + 1) & 63;
    const int voLs = __shfl(vo7, iL), vaLs = __shfl(va7, iL);
    const int voRs = __shfl(vo0, iR), vaRs = __shfl(va0, iR);
    const int voL = (lane == 0)  ? vo0 : voLs;
    const int vaL = (lane == 0)  ? va0 : vaLs;
    const int voR = (lane == 63) ? vo7 : voRs;
    const int vaR = (lane == 63) ? va7 : vaRs;

    // ---- horizontal 3-window OR / AND
    const int ho0 = voL | vo0 | vo1;  const int ha0 = vaL & va0 & va1;
    const int ho1 = vo0 | vo1 | vo2;  const int ha1 = va0 & va1 & va2;
    const int ho2 = vo1 | vo2 | vo3;  const int ha2 = va1 & va2 & va3;
    const int ho3 = vo2 | vo3 | vo4;  const int ha3 = va2 & va3 & va4;
    const int ho4 = vo3 | vo4 | vo5;  const int ha4 = va3 & va4 & va5;
    const int ho5 = vo4 | vo5 | vo6;  const int ha5 = va4 & va5 & va6;
    const int ho6 = vo5 | vo6 | vo7;  const int ha6 = va5 & va6 & va7;
    const int ho7 = vo6 | vo7 | voR;  const int ha7 = va6 & va7 & vaR;

    // ---- per-pixel: max(x,0) - x*m + ln(1+e^{-|x|})  ==  max(m?-x:x, 0) + softplus
    //      weight = 1 + border,  border = ho ^ ha  (OR superset of AND)
    float acc = 0.0f;
#define PX(xf, m, ho, ha) { \
        const float ls = fmaxf((m) ? -(xf) : (xf), 0.0f) \
                       + __logf(1.0f + __expf(-fabsf(xf))); \
        const float wf = (float)(1 + ((ho) ^ (ha))); \
        acc = fmaf(ls, wf, acc); }
    PX(xa.x, c0.x, ho0, ha0)
    PX(xa.y, c0.y, ho1, ha1)
    PX(xa.z, c0.z, ho2, ha2)
    PX(xa.w, c0.w, ho3, ha3)
    PX(xb.x, c1.x, ho4, ha4)
    PX(xb.y, c1.y, ho5, ha5)
    PX(xb.z, c1.z, ho6, ha6)
    PX(xb.w, c1.w, ho7, ha7)
#undef PX

    // ---- reduction: wave shuffle + tiny LDS across 4 waves
    #pragma unroll
    for (int off = 32; off > 0; off >>= 1)
        acc += __shfl_down(acc, off);
    if ((tid & 63) == 0) wsum[tid >> 6] = acc;
    __syncthreads();
    if (tid == 0) {
        const float t = wsum[0] + wsum[1] + wsum[2] + wsum[3];
        if (atomic_mode) atomicAdd(part, t * INV_TOTAL);
        else             part[blockIdx.x] = t;
    }
}

__global__ __launch_bounds__(256) void border_loss_reduce(
    const float* __restrict__ part, float* __restrict__ out)
{
    __shared__ float wsum[4];
    float t = 0.0f;
    for (int i = threadIdx.x; i < NBLK; i += 256) t += part[i];
    #pragma unroll
    for (int off = 32; off > 0; off >>= 1)
        t += __shfl_down(t, off);
    if ((threadIdx.x & 63) == 0) wsum[threadIdx.x >> 6] = t;
    __syncthreads();
    if (threadIdx.x == 0)
        out[0] = (wsum[0] + wsum[1] + wsum[2] + wsum[3]) * INV_TOTAL;
}

__global__ void border_loss_zero(float* out) { out[0] = 0.0f; }

extern "C" void kernel_launch(void* const* d_in, const int* in_sizes, int n_in,
                              void* d_out, int out_size, void* d_ws, size_t ws_size,
                              hipStream_t stream)
{
    const float* x = (const float*)d_in[0];
    const int*   y = (const int*)d_in[1];
    float* out = (float*)d_out;

    if (ws_size >= (size_t)NBLK * sizeof(float)) {
        // Deterministic two-stage reduction via workspace partials.
        float* part = (float*)d_ws;
        border_loss_main<<<NBLK, 256, 0, stream>>>(x, y, part, 0);
        border_loss_reduce<<<1, 256, 0, stream>>>(part, out);
    } else {
        // Fallback: zero output then atomic accumulation.
        border_loss_zero<<<1, 1, 0, stream>>>(out);
        border_loss_main<<<NBLK, 256, 0, stream>>>(x, y, out, 1);
    }
}